// Round 4
// baseline (422.519 us; speedup 1.0000x reference)
//
#include <hip/hip_runtime.h>

constexpr int FIN = 128;   // input features
constexpr int HH  = 64;    // half hidden (GCN branch width)

// ---- bf16 helpers (manual, RNE) ----
__device__ __forceinline__ unsigned short f2bf(float f) {
    unsigned u = __float_as_uint(f);
    u += 0x7FFFu + ((u >> 16) & 1u);
    return (unsigned short)(u >> 16);
}

// ------------------------------------------------------------------ GEMM ----
// [xwg | xwf] = x[N,128] @ [W1 | Wf1];  xwg = bf16 GCN half, xwf = fp32 half
__global__ __launch_bounds__(256) void k_gemm(
    const float* __restrict__ x, const float* __restrict__ W1,
    const float* __restrict__ Wf1, unsigned short* __restrict__ xwg,
    float* __restrict__ xwf, int N)
{
    __shared__ float xs[16][68];     // [k][node], +4 pad
    __shared__ float ws[16][128];    // [k][col]

    const int tid = threadIdx.x;
    const int tx  = tid & 31;        // col group: cols tx*4 .. tx*4+3
    const int ty  = tid >> 5;        // node group: nodes ty*8 .. ty*8+7
    const int nbase = blockIdx.x * 64;

    float acc[8][4];
#pragma unroll
    for (int i = 0; i < 8; ++i)
#pragma unroll
        for (int j = 0; j < 4; ++j) acc[i][j] = 0.0f;

    const int xr_row = tid >> 2;
    const int xr_kk0 = (tid & 3) * 4;
    int nload = nbase + xr_row;
    const int nclamped = (nload < N) ? nload : (N - 1);

    const int wk = tid >> 4;
    const int wc = (tid * 8) & 127;

    for (int k0 = 0; k0 < FIN; k0 += 16) {
        float4 xv = *(const float4*)(x + (size_t)nclamped * FIN + k0 + xr_kk0);
        xs[xr_kk0 + 0][xr_row] = xv.x;
        xs[xr_kk0 + 1][xr_row] = xv.y;
        xs[xr_kk0 + 2][xr_row] = xv.z;
        xs[xr_kk0 + 3][xr_row] = xv.w;
        {
            const float* src = (wc < HH) ? (W1  + (size_t)(k0 + wk) * HH + wc)
                                         : (Wf1 + (size_t)(k0 + wk) * HH + (wc - HH));
            float4 w0 = *(const float4*)(src);
            float4 w1 = *(const float4*)(src + 4);
            *(float4*)&ws[wk][wc]     = w0;
            *(float4*)&ws[wk][wc + 4] = w1;
        }
        __syncthreads();

#pragma unroll
        for (int kk = 0; kk < 16; ++kk) {
            float4 xa = *(const float4*)&xs[kk][ty * 8];
            float4 xb = *(const float4*)&xs[kk][ty * 8 + 4];
            float4 wv = *(const float4*)&ws[kk][tx * 4];
            float xr[8] = {xa.x, xa.y, xa.z, xa.w, xb.x, xb.y, xb.z, xb.w};
#pragma unroll
            for (int i = 0; i < 8; ++i) {
                acc[i][0] = fmaf(xr[i], wv.x, acc[i][0]);
                acc[i][1] = fmaf(xr[i], wv.y, acc[i][1]);
                acc[i][2] = fmaf(xr[i], wv.z, acc[i][2]);
                acc[i][3] = fmaf(xr[i], wv.w, acc[i][3]);
            }
        }
        __syncthreads();
    }

#pragma unroll
    for (int i = 0; i < 8; ++i) {
        int n = nbase + ty * 8 + i;
        if (n < N) {
            if (tx < 16) {   // GCN half -> bf16
                ushort4 v;
                v.x = f2bf(acc[i][0]); v.y = f2bf(acc[i][1]);
                v.z = f2bf(acc[i][2]); v.w = f2bf(acc[i][3]);
                *(ushort4*)(xwg + (size_t)n * HH + tx * 4) = v;
            } else {         // linear half -> fp32
                float4 v = make_float4(acc[i][0], acc[i][1], acc[i][2], acc[i][3]);
                *(float4*)(xwf + (size_t)n * HH + (tx - 16) * 4) = v;
            }
        }
    }
}

// ------------------------------------------------------------ CSR build -----
__global__ void k_count(const int* __restrict__ col, int* __restrict__ cnt, int E) {
    int e = blockIdx.x * blockDim.x + threadIdx.x;
    if (e < E) atomicAdd(cnt + col[e], 1);
}

__global__ __launch_bounds__(256) void k_scan1(
    const int* __restrict__ cnt, int* __restrict__ off, int* __restrict__ bsum, int N)
{
    __shared__ int s[256];
    const int t = threadIdx.x;
    const int idx = blockIdx.x * 1024 + t * 4;
    int v[4]; int mysum = 0;
#pragma unroll
    for (int j = 0; j < 4; ++j) {
        v[j] = (idx + j < N) ? cnt[idx + j] : 0;
        mysum += v[j];
    }
    s[t] = mysum;
    __syncthreads();
    for (int o = 1; o < 256; o <<= 1) {
        int y = (t >= o) ? s[t - o] : 0;
        __syncthreads();
        s[t] += y;
        __syncthreads();
    }
    int running = s[t] - mysum;
#pragma unroll
    for (int j = 0; j < 4; ++j) {
        if (idx + j < N) off[idx + j] = running;
        running += v[j];
    }
    if (t == 255) bsum[blockIdx.x] = s[255];
}

__global__ void k_scan2(int* __restrict__ bsum, int nb) {
    if (threadIdx.x == 0 && blockIdx.x == 0) {
        int run = 0;
        for (int i = 0; i < nb; ++i) { int v = bsum[i]; bsum[i] = run; run += v; }
    }
}

__global__ void k_scan3(const int* __restrict__ cnt, int* __restrict__ off,
                        int* __restrict__ cur, const int* __restrict__ bsum,
                        float* __restrict__ dinv, int N)
{
    int i = blockIdx.x * blockDim.x + threadIdx.x;
    if (i < N) {
        int o = off[i] + bsum[i >> 10];
        off[i] = o;
        cur[i] = o;
        dinv[i] = rsqrtf((float)cnt[i] + 1.0f);
    }
}

// srow[pos] = row, grouped by target col (4B records; norm recomputed later)
__global__ void k_scatter(const int* __restrict__ ei, int* __restrict__ cur,
                          int* __restrict__ srow, int E)
{
    int e = blockIdx.x * blockDim.x + threadIdx.x;
    if (e >= E) return;
    int r = ei[e], c = ei[E + e];
    int pos = atomicAdd(cur + c, 1);
    srow[pos] = r;
}

// ------------------------- fused: layer-1 aggregate + relu + layer-2 dots ---
// one wave per node; 4 groups of 16 lanes process 4 edges concurrently,
// each lane loads 4 bf16 features (16 lanes cover the 64 GCN features).
__global__ __launch_bounds__(256) void k_fused(
    const int* __restrict__ off, const int* __restrict__ cur,
    const int* __restrict__ srow, const float* __restrict__ dinv,
    const unsigned short* __restrict__ xwg, const float* __restrict__ xwf,
    const float* __restrict__ b1, const float* __restrict__ bf1,
    const float* __restrict__ W2, const float* __restrict__ Wf2,
    const float* __restrict__ b2, const float* __restrict__ bf2,
    float* __restrict__ z, float* __restrict__ out, int N)
{
    const int wid  = (blockIdx.x * blockDim.x + threadIdx.x) >> 6;  // node id
    const int lane = threadIdx.x & 63;
    const int g    = lane >> 4;        // edge group 0..3
    const int l16  = lane & 15;        // feature quad: features l16*4..+3
    const int i    = (wid < N) ? wid : (N - 1);

    const int jb  = off[i];
    const int deg = cur[i] - jb;
    const float di = dinv[i];

    // one coalesced load grabs the whole edge list (deg <= 64 virtually always)
    int   erow = i;
    float enrm = 0.0f;
    if (lane < deg) {
        erow = srow[jb + lane];
        enrm = dinv[erow] * di;
    }

    float4 acc = make_float4(0.f, 0.f, 0.f, 0.f);
    const int lim = (deg < 64) ? deg : 64;
    for (int t0 = 0; t0 < lim; t0 += 4) {
        int  tt    = t0 + g;
        bool valid = tt < lim;
        int  row   = __shfl(erow, tt, 64);
        float s    = __shfl(enrm, tt, 64);
        row        = valid ? row : i;
        s          = valid ? s : 0.0f;
        uint2 p = *(const uint2*)(xwg + (size_t)row * HH + l16 * 4);
        acc.x = fmaf(__uint_as_float(p.x << 16),          s, acc.x);
        acc.y = fmaf(__uint_as_float(p.x & 0xFFFF0000u),  s, acc.y);
        acc.z = fmaf(__uint_as_float(p.y << 16),          s, acc.z);
        acc.w = fmaf(__uint_as_float(p.y & 0xFFFF0000u),  s, acc.w);
    }
    // rare tail: deg > 64
    for (int j = jb + 64 + g; j < jb + deg; j += 4) {
        int row = srow[j];
        float s = dinv[row] * di;
        uint2 p = *(const uint2*)(xwg + (size_t)row * HH + l16 * 4);
        acc.x = fmaf(__uint_as_float(p.x << 16),          s, acc.x);
        acc.y = fmaf(__uint_as_float(p.x & 0xFFFF0000u),  s, acc.y);
        acc.z = fmaf(__uint_as_float(p.y << 16),          s, acc.z);
        acc.w = fmaf(__uint_as_float(p.y & 0xFFFF0000u),  s, acc.w);
    }

    // combine the 4 edge-groups
    acc.x += __shfl_xor(acc.x, 16, 64); acc.x += __shfl_xor(acc.x, 32, 64);
    acc.y += __shfl_xor(acc.y, 16, 64); acc.y += __shfl_xor(acc.y, 32, 64);
    acc.z += __shfl_xor(acc.z, 16, 64); acc.z += __shfl_xor(acc.z, 32, 64);
    acc.w += __shfl_xor(acc.w, 16, 64); acc.w += __shfl_xor(acc.w, 32, 64);

    // self loop
    {
        float dd = di * di;
        uint2 p = *(const uint2*)(xwg + (size_t)i * HH + l16 * 4);
        acc.x = fmaf(__uint_as_float(p.x << 16),          dd, acc.x);
        acc.y = fmaf(__uint_as_float(p.x & 0xFFFF0000u),  dd, acc.y);
        acc.z = fmaf(__uint_as_float(p.y << 16),          dd, acc.z);
        acc.w = fmaf(__uint_as_float(p.y & 0xFFFF0000u),  dd, acc.w);
    }

    // epilogue: relu + two 128-dots (groups are redundant replicas)
    float4 b1v  = *(const float4*)(b1  + l16 * 4);
    float4 bf1v = *(const float4*)(bf1 + l16 * 4);
    float4 x1   = *(const float4*)(xwf + (size_t)i * HH + l16 * 4);
    float4 h0, h1;
    h0.x = fmaxf(acc.x + b1v.x, 0.f);  h0.y = fmaxf(acc.y + b1v.y, 0.f);
    h0.z = fmaxf(acc.z + b1v.z, 0.f);  h0.w = fmaxf(acc.w + b1v.w, 0.f);
    h1.x = fmaxf(x1.x + bf1v.x, 0.f);  h1.y = fmaxf(x1.y + bf1v.y, 0.f);
    h1.z = fmaxf(x1.z + bf1v.z, 0.f);  h1.w = fmaxf(x1.w + bf1v.w, 0.f);

    float4 w2a  = *(const float4*)(W2  + l16 * 4);
    float4 w2b  = *(const float4*)(W2  + HH + l16 * 4);
    float4 wf2a = *(const float4*)(Wf2 + l16 * 4);
    float4 wf2b = *(const float4*)(Wf2 + HH + l16 * 4);

    float zp = h0.x * w2a.x + h0.y * w2a.y + h0.z * w2a.z + h0.w * w2a.w
             + h1.x * w2b.x + h1.y * w2b.y + h1.z * w2b.z + h1.w * w2b.w;
    float fp = h0.x * wf2a.x + h0.y * wf2a.y + h0.z * wf2a.z + h0.w * wf2a.w
             + h1.x * wf2b.x + h1.y * wf2b.y + h1.z * wf2b.z + h1.w * wf2b.w;
#pragma unroll
    for (int o = 8; o > 0; o >>= 1) {
        zp += __shfl_xor(zp, o, 64);
        fp += __shfl_xor(fp, o, 64);
    }
    if (lane == 0 && wid < N) {
        z[i]   = zp;
        out[i] = fp + b2[0] + bf2[0];
    }
}

// ------------------------------------------- layer-2 aggregate (CSR) --------
// one wave per 4 nodes: 16 lanes stride a node's edge list in parallel
__global__ __launch_bounds__(256) void k_agg2(
    const int* __restrict__ off, const int* __restrict__ cur,
    const int* __restrict__ srow, const float* __restrict__ dinv,
    const float* __restrict__ z, float* __restrict__ out, int N)
{
    const int wid  = (blockIdx.x * blockDim.x + threadIdx.x) >> 6;
    const int lane = threadIdx.x & 63;
    const int g    = lane >> 4;
    const int l16  = lane & 15;
    int i = wid * 4 + g;
    bool ok = (i < N);
    i = ok ? i : (N - 1);

    const int jb = off[i], je = cur[i];
    const float di = dinv[i];
    float s = 0.0f;
    for (int j = jb + l16; j < je; j += 16) {
        int r = srow[j];
        s = fmaf(z[r], dinv[r] * di, s);
    }
#pragma unroll
    for (int o = 8; o > 0; o >>= 1) s += __shfl_xor(s, o, 64);
    if (l16 == 0 && ok) {
        out[i] += fmaf(z[i], di * di, s);
    }
}

// ---------------------------------------------------------------- launch ----
extern "C" void kernel_launch(void* const* d_in, const int* in_sizes, int n_in,
                              void* d_out, int out_size, void* d_ws, size_t ws_size,
                              hipStream_t stream)
{
    const float* x   = (const float*)d_in[0];
    const int*   ei  = (const int*)d_in[1];    // [2,E]: row=ei[e], col=ei[E+e]
    const float* W1  = (const float*)d_in[2];
    const float* b1  = (const float*)d_in[3];
    const float* Wf1 = (const float*)d_in[4];
    const float* bf1 = (const float*)d_in[5];
    const float* W2  = (const float*)d_in[6];
    const float* b2  = (const float*)d_in[7];
    const float* Wf2 = (const float*)d_in[8];
    const float* bf2 = (const float*)d_in[9];

    const int N = in_sizes[0] / FIN;   // 100000
    const int E = in_sizes[1] / 2;     // 1600000
    float* out = (float*)d_out;

    // workspace layout (all segments 8B-aligned):
    // xwf[N*64] f32 | xwg[N*64] bf16 | dinv[N] | z[N] | cnt[N] | off[N] | cur[N] | bsum | srow[E]
    const int nb = (N + 1023) / 1024;
    float*          xwf  = (float*)d_ws;
    unsigned short* xwg  = (unsigned short*)(xwf + (size_t)N * HH);
    float*          dinv = (float*)(xwg + (size_t)N * HH);
    float*          z    = dinv + N;
    int*            cnt  = (int*)(z + N);
    int*            off  = cnt + N;
    int*            cur  = off + N;
    int*            bsum = cur + N;
    int             bpad = (nb + 2) & ~1;
    int*            srow = bsum + bpad;

    hipMemsetAsync(cnt, 0, (size_t)N * sizeof(int), stream);

    k_count<<<(E + 255) / 256, 256, 0, stream>>>(ei + E, cnt, E);
    k_scan1<<<nb, 256, 0, stream>>>(cnt, off, bsum, N);
    k_scan2<<<1, 64, 0, stream>>>(bsum, nb);
    k_scan3<<<(N + 255) / 256, 256, 0, stream>>>(cnt, off, cur, bsum, dinv, N);
    k_scatter<<<(E + 255) / 256, 256, 0, stream>>>(ei, cur, srow, E);

    k_gemm<<<(N + 63) / 64, 256, 0, stream>>>(x, W1, Wf1, xwg, xwf, N);

    {
        long threads = (long)N * 64;           // one wave per node
        int blocks = (int)((threads + 255) / 256);
        k_fused<<<blocks, 256, 0, stream>>>(off, cur, srow, dinv, xwg, xwf,
                                            b1, bf1, W2, Wf2, b2, bf2, z, out, N);
    }

    {
        long waves = ((long)N + 3) / 4;        // one wave per 4 nodes
        int blocks = (int)((waves * 64 + 255) / 256);
        k_agg2<<<blocks, 256, 0, stream>>>(off, cur, srow, dinv, z, out, N);
    }
}

// Round 5
// 386.149 us; speedup vs baseline: 1.0942x; 1.0942x over previous
//
#include <hip/hip_runtime.h>

constexpr int FIN = 128;   // input features
constexpr int HH  = 64;    // half hidden (GCN branch width)

// ---- bf16 helpers (manual, RNE) ----
__device__ __forceinline__ unsigned short f2bf(float f) {
    unsigned u = __float_as_uint(f);
    u += 0x7FFFu + ((u >> 16) & 1u);
    return (unsigned short)(u >> 16);
}

// ------------------------------------------------------------------ GEMM ----
// [xwg | xwf] = x[N,128] @ [W1 | Wf1];  xwg = bf16 GCN half, xwf = fp32 half
__global__ __launch_bounds__(256) void k_gemm(
    const float* __restrict__ x, const float* __restrict__ W1,
    const float* __restrict__ Wf1, unsigned short* __restrict__ xwg,
    float* __restrict__ xwf, int N)
{
    __shared__ float xs[16][68];     // [k][node], +4 pad
    __shared__ float ws[16][128];    // [k][col]

    const int tid = threadIdx.x;
    const int tx  = tid & 31;        // col group: cols tx*4 .. tx*4+3
    const int ty  = tid >> 5;        // node group: nodes ty*8 .. ty*8+7
    const int nbase = blockIdx.x * 64;

    float acc[8][4];
#pragma unroll
    for (int i = 0; i < 8; ++i)
#pragma unroll
        for (int j = 0; j < 4; ++j) acc[i][j] = 0.0f;

    const int xr_row = tid >> 2;
    const int xr_kk0 = (tid & 3) * 4;
    int nload = nbase + xr_row;
    const int nclamped = (nload < N) ? nload : (N - 1);

    const int wk = tid >> 4;
    const int wc = (tid * 8) & 127;

    for (int k0 = 0; k0 < FIN; k0 += 16) {
        float4 xv = *(const float4*)(x + (size_t)nclamped * FIN + k0 + xr_kk0);
        xs[xr_kk0 + 0][xr_row] = xv.x;
        xs[xr_kk0 + 1][xr_row] = xv.y;
        xs[xr_kk0 + 2][xr_row] = xv.z;
        xs[xr_kk0 + 3][xr_row] = xv.w;
        {
            const float* src = (wc < HH) ? (W1  + (size_t)(k0 + wk) * HH + wc)
                                         : (Wf1 + (size_t)(k0 + wk) * HH + (wc - HH));
            float4 w0 = *(const float4*)(src);
            float4 w1 = *(const float4*)(src + 4);
            *(float4*)&ws[wk][wc]     = w0;
            *(float4*)&ws[wk][wc + 4] = w1;
        }
        __syncthreads();

#pragma unroll
        for (int kk = 0; kk < 16; ++kk) {
            float4 xa = *(const float4*)&xs[kk][ty * 8];
            float4 xb = *(const float4*)&xs[kk][ty * 8 + 4];
            float4 wv = *(const float4*)&ws[kk][tx * 4];
            float xr[8] = {xa.x, xa.y, xa.z, xa.w, xb.x, xb.y, xb.z, xb.w};
#pragma unroll
            for (int i = 0; i < 8; ++i) {
                acc[i][0] = fmaf(xr[i], wv.x, acc[i][0]);
                acc[i][1] = fmaf(xr[i], wv.y, acc[i][1]);
                acc[i][2] = fmaf(xr[i], wv.z, acc[i][2]);
                acc[i][3] = fmaf(xr[i], wv.w, acc[i][3]);
            }
        }
        __syncthreads();
    }

#pragma unroll
    for (int i = 0; i < 8; ++i) {
        int n = nbase + ty * 8 + i;
        if (n < N) {
            if (tx < 16) {   // GCN half -> bf16
                ushort4 v;
                v.x = f2bf(acc[i][0]); v.y = f2bf(acc[i][1]);
                v.z = f2bf(acc[i][2]); v.w = f2bf(acc[i][3]);
                *(ushort4*)(xwg + (size_t)n * HH + tx * 4) = v;
            } else {         // linear half -> fp32
                float4 v = make_float4(acc[i][0], acc[i][1], acc[i][2], acc[i][3]);
                *(float4*)(xwf + (size_t)n * HH + (tx - 16) * 4) = v;
            }
        }
    }
}

// ------------------------------------------------------------ CSR build -----
__global__ void k_count(const int* __restrict__ col, int* __restrict__ cnt, int E) {
    int e = blockIdx.x * blockDim.x + threadIdx.x;
    if (e < E) atomicAdd(cnt + col[e], 1);
}

__global__ __launch_bounds__(256) void k_scan1(
    const int* __restrict__ cnt, int* __restrict__ off, int* __restrict__ bsum, int N)
{
    __shared__ int s[256];
    const int t = threadIdx.x;
    const int idx = blockIdx.x * 1024 + t * 4;
    int v[4]; int mysum = 0;
#pragma unroll
    for (int j = 0; j < 4; ++j) {
        v[j] = (idx + j < N) ? cnt[idx + j] : 0;
        mysum += v[j];
    }
    s[t] = mysum;
    __syncthreads();
    for (int o = 1; o < 256; o <<= 1) {
        int y = (t >= o) ? s[t - o] : 0;
        __syncthreads();
        s[t] += y;
        __syncthreads();
    }
    int running = s[t] - mysum;
#pragma unroll
    for (int j = 0; j < 4; ++j) {
        if (idx + j < N) off[idx + j] = running;
        running += v[j];
    }
    if (t == 255) bsum[blockIdx.x] = s[255];
}

__global__ void k_scan2(int* __restrict__ bsum, int nb) {
    if (threadIdx.x == 0 && blockIdx.x == 0) {
        int run = 0;
        for (int i = 0; i < nb; ++i) { int v = bsum[i]; bsum[i] = run; run += v; }
    }
}

__global__ void k_scan3(const int* __restrict__ cnt, int* __restrict__ off,
                        int* __restrict__ cur, const int* __restrict__ bsum,
                        float* __restrict__ dinv, int N)
{
    int i = blockIdx.x * blockDim.x + threadIdx.x;
    if (i < N) {
        int o = off[i] + bsum[i >> 10];
        off[i] = o;
        cur[i] = o;
        dinv[i] = rsqrtf((float)cnt[i] + 1.0f);
    }
}

// sedge[pos] = {row, norm} grouped by target col; 8B non-temporal store
__global__ void k_scatter(const int* __restrict__ ei, int* __restrict__ cur,
                          const float* __restrict__ dinv, int2* __restrict__ sedge, int E)
{
    int e = blockIdx.x * blockDim.x + threadIdx.x;
    if (e >= E) return;
    int r = ei[e], c = ei[E + e];
    float nrm = dinv[r] * dinv[c];
    int pos = atomicAdd(cur + c, 1);
    unsigned long long rec = (unsigned)r |
        ((unsigned long long)__float_as_uint(nrm) << 32);
    __builtin_nontemporal_store(rec, (unsigned long long*)(sedge + pos));
}

// ------------------------- fused: layer-1 aggregate + relu + layer-2 dots ---
// one wave per node; 4 groups of 16 lanes process 4 edges concurrently,
// each lane loads 4 bf16 features (16 lanes cover the 64 GCN features).
__global__ __launch_bounds__(256) void k_fused(
    const int* __restrict__ off, const int* __restrict__ cur,
    const int2* __restrict__ sedge, const float* __restrict__ dinv,
    const unsigned short* __restrict__ xwg, const float* __restrict__ xwf,
    const float* __restrict__ b1, const float* __restrict__ bf1,
    const float* __restrict__ W2, const float* __restrict__ Wf2,
    const float* __restrict__ b2, const float* __restrict__ bf2,
    float* __restrict__ z, float* __restrict__ out, int N)
{
    const int wid  = (blockIdx.x * blockDim.x + threadIdx.x) >> 6;  // node id
    const int lane = threadIdx.x & 63;
    const int g    = lane >> 4;        // edge group 0..3
    const int l16  = lane & 15;        // feature quad: features l16*4..+3
    const int i    = (wid < N) ? wid : (N - 1);

    const int jb  = off[i];
    const int deg = cur[i] - jb;
    const float di = dinv[i];

    // one coalesced load grabs the whole edge list (deg <= 64 virtually always)
    int2 er = make_int2(i, 0);
    if (lane < deg) er = sedge[jb + lane];

    float4 acc = make_float4(0.f, 0.f, 0.f, 0.f);
    const int lim = (deg < 64) ? deg : 64;
    for (int t0 = 0; t0 < lim; t0 += 4) {
        int  tt    = t0 + g;
        bool valid = tt < lim;
        int  row   = __shfl(er.x, tt, 64);
        float s    = __shfl(__int_as_float(er.y), tt, 64);
        row        = valid ? row : i;
        s          = valid ? s : 0.0f;
        uint2 p = *(const uint2*)(xwg + (size_t)row * HH + l16 * 4);
        acc.x = fmaf(__uint_as_float(p.x << 16),          s, acc.x);
        acc.y = fmaf(__uint_as_float(p.x & 0xFFFF0000u),  s, acc.y);
        acc.z = fmaf(__uint_as_float(p.y << 16),          s, acc.z);
        acc.w = fmaf(__uint_as_float(p.y & 0xFFFF0000u),  s, acc.w);
    }
    // rare tail: deg > 64
    for (int j = jb + 64 + g; j < jb + deg; j += 4) {
        int2 ep = sedge[j];
        float s = __int_as_float(ep.y);
        uint2 p = *(const uint2*)(xwg + (size_t)ep.x * HH + l16 * 4);
        acc.x = fmaf(__uint_as_float(p.x << 16),          s, acc.x);
        acc.y = fmaf(__uint_as_float(p.x & 0xFFFF0000u),  s, acc.y);
        acc.z = fmaf(__uint_as_float(p.y << 16),          s, acc.z);
        acc.w = fmaf(__uint_as_float(p.y & 0xFFFF0000u),  s, acc.w);
    }

    // combine the 4 edge-groups
    acc.x += __shfl_xor(acc.x, 16, 64); acc.x += __shfl_xor(acc.x, 32, 64);
    acc.y += __shfl_xor(acc.y, 16, 64); acc.y += __shfl_xor(acc.y, 32, 64);
    acc.z += __shfl_xor(acc.z, 16, 64); acc.z += __shfl_xor(acc.z, 32, 64);
    acc.w += __shfl_xor(acc.w, 16, 64); acc.w += __shfl_xor(acc.w, 32, 64);

    // self loop
    {
        float dd = di * di;
        uint2 p = *(const uint2*)(xwg + (size_t)i * HH + l16 * 4);
        acc.x = fmaf(__uint_as_float(p.x << 16),          dd, acc.x);
        acc.y = fmaf(__uint_as_float(p.x & 0xFFFF0000u),  dd, acc.y);
        acc.z = fmaf(__uint_as_float(p.y << 16),          dd, acc.z);
        acc.w = fmaf(__uint_as_float(p.y & 0xFFFF0000u),  dd, acc.w);
    }

    // epilogue: relu + two 128-dots (groups are redundant replicas)
    float4 b1v  = *(const float4*)(b1  + l16 * 4);
    float4 bf1v = *(const float4*)(bf1 + l16 * 4);
    float4 x1   = *(const float4*)(xwf + (size_t)i * HH + l16 * 4);
    float4 h0, h1;
    h0.x = fmaxf(acc.x + b1v.x, 0.f);  h0.y = fmaxf(acc.y + b1v.y, 0.f);
    h0.z = fmaxf(acc.z + b1v.z, 0.f);  h0.w = fmaxf(acc.w + b1v.w, 0.f);
    h1.x = fmaxf(x1.x + bf1v.x, 0.f);  h1.y = fmaxf(x1.y + bf1v.y, 0.f);
    h1.z = fmaxf(x1.z + bf1v.z, 0.f);  h1.w = fmaxf(x1.w + bf1v.w, 0.f);

    float4 w2a  = *(const float4*)(W2  + l16 * 4);
    float4 w2b  = *(const float4*)(W2  + HH + l16 * 4);
    float4 wf2a = *(const float4*)(Wf2 + l16 * 4);
    float4 wf2b = *(const float4*)(Wf2 + HH + l16 * 4);

    float zp = h0.x * w2a.x + h0.y * w2a.y + h0.z * w2a.z + h0.w * w2a.w
             + h1.x * w2b.x + h1.y * w2b.y + h1.z * w2b.z + h1.w * w2b.w;
    float fp = h0.x * wf2a.x + h0.y * wf2a.y + h0.z * wf2a.z + h0.w * wf2a.w
             + h1.x * wf2b.x + h1.y * wf2b.y + h1.z * wf2b.z + h1.w * wf2b.w;
#pragma unroll
    for (int o = 8; o > 0; o >>= 1) {
        zp += __shfl_xor(zp, o, 64);
        fp += __shfl_xor(fp, o, 64);
    }
    if (lane == 0 && wid < N) {
        z[i]   = zp;
        out[i] = fp + b2[0] + bf2[0];
    }
}

// ------------------------------------------- layer-2 aggregate (CSR) --------
// one wave per 4 nodes: 16 lanes stride a node's edge list in parallel
__global__ __launch_bounds__(256) void k_agg2(
    const int* __restrict__ off, const int* __restrict__ cur,
    const int2* __restrict__ sedge, const float* __restrict__ dinv,
    const float* __restrict__ z, float* __restrict__ out, int N)
{
    const int wid  = (blockIdx.x * blockDim.x + threadIdx.x) >> 6;
    const int lane = threadIdx.x & 63;
    const int g    = lane >> 4;
    const int l16  = lane & 15;
    int i = wid * 4 + g;
    bool ok = (i < N);
    i = ok ? i : (N - 1);

    const int jb = off[i], je = cur[i];
    float s = 0.0f;
    for (int j = jb + l16; j < je; j += 16) {
        int2 ep = sedge[j];
        s = fmaf(z[ep.x], __int_as_float(ep.y), s);
    }
#pragma unroll
    for (int o = 8; o > 0; o >>= 1) s += __shfl_xor(s, o, 64);
    if (l16 == 0 && ok) {
        float di = dinv[i];
        out[i] += fmaf(z[i], di * di, s);
    }
}

// ---------------------------------------------------------------- launch ----
extern "C" void kernel_launch(void* const* d_in, const int* in_sizes, int n_in,
                              void* d_out, int out_size, void* d_ws, size_t ws_size,
                              hipStream_t stream)
{
    const float* x   = (const float*)d_in[0];
    const int*   ei  = (const int*)d_in[1];    // [2,E]: row=ei[e], col=ei[E+e]
    const float* W1  = (const float*)d_in[2];
    const float* b1  = (const float*)d_in[3];
    const float* Wf1 = (const float*)d_in[4];
    const float* bf1 = (const float*)d_in[5];
    const float* W2  = (const float*)d_in[6];
    const float* b2  = (const float*)d_in[7];
    const float* Wf2 = (const float*)d_in[8];
    const float* bf2 = (const float*)d_in[9];

    const int N = in_sizes[0] / FIN;   // 100000
    const int E = in_sizes[1] / 2;     // 1600000
    float* out = (float*)d_out;

    // workspace layout (all segments 8B-aligned):
    // xwf[N*64] f32 | xwg[N*64] bf16 | dinv[N] | z[N] | cnt[N] | off[N] | cur[N] | bsum | sedge[2E]
    const int nb = (N + 1023) / 1024;
    float*          xwf  = (float*)d_ws;
    unsigned short* xwg  = (unsigned short*)(xwf + (size_t)N * HH);
    float*          dinv = (float*)(xwg + (size_t)N * HH);
    float*          z    = dinv + N;
    int*            cnt  = (int*)(z + N);
    int*            off  = cnt + N;
    int*            cur  = off + N;
    int*            bsum = cur + N;
    int             bpad = (nb + 2) & ~1;
    int2*           sedge = (int2*)(bsum + bpad);

    hipMemsetAsync(cnt, 0, (size_t)N * sizeof(int), stream);

    k_count<<<(E + 255) / 256, 256, 0, stream>>>(ei + E, cnt, E);
    k_scan1<<<nb, 256, 0, stream>>>(cnt, off, bsum, N);
    k_scan2<<<1, 64, 0, stream>>>(bsum, nb);
    k_scan3<<<(N + 255) / 256, 256, 0, stream>>>(cnt, off, cur, bsum, dinv, N);
    k_scatter<<<(E + 255) / 256, 256, 0, stream>>>(ei, cur, dinv, sedge, E);

    k_gemm<<<(N + 63) / 64, 256, 0, stream>>>(x, W1, Wf1, xwg, xwf, N);

    {
        long threads = (long)N * 64;           // one wave per node
        int blocks = (int)((threads + 255) / 256);
        k_fused<<<blocks, 256, 0, stream>>>(off, cur, sedge, dinv, xwg, xwf,
                                            b1, bf1, W2, Wf2, b2, bf2, z, out, N);
    }

    {
        long waves = ((long)N + 3) / 4;        // one wave per 4 nodes
        int blocks = (int)((waves * 64 + 255) / 256);
        k_agg2<<<blocks, 256, 0, stream>>>(off, cur, sedge, dinv, z, out, N);
    }
}